// Round 1
// baseline (1632.697 us; speedup 1.0000x reference)
//
#include <hip/hip_runtime.h>

// PerturbationModel: scores = counts @ log_mix^T (+ log comm bias), LSE over K, grand sum.
// G=3 S=10 N=5000 K=20 O=1000. counts 600 MB fp32 -> memory-bound, floor ~95 us.

#define EPSF 1e-6f
constexpr int Gc = 3, Sc = 10, Nc = 5000, Kc = 20, Oc = 1000;
constexpr int ROWS_PER_G = Sc * Nc;                 // 50000
constexpr int GRAN_ROWS  = 8;                       // rows per wave-granule (2 lane-rows x 4 reg-rows)
constexpr int GRANS_PER_G = ROWS_PER_G / GRAN_ROWS; // 6250 (exact)
constexpr int LM_ELEMS = Kc * Oc;                   // 20000
constexpr int LM_ALLOC = LM_ELEMS + 32;             // guard pad for tail-lane b128 reads

// 32-lane-group sum via DPP (VALU pipe only). Result valid in lanes 31 and 63.
__device__ __forceinline__ float red32(float v) {
  v += __int_as_float(__builtin_amdgcn_update_dpp(0, __float_as_int(v), 0x111, 0xF, 0xF, true)); // row_shr:1
  v += __int_as_float(__builtin_amdgcn_update_dpp(0, __float_as_int(v), 0x112, 0xF, 0xF, true)); // row_shr:2
  v += __int_as_float(__builtin_amdgcn_update_dpp(0, __float_as_int(v), 0x114, 0xF, 0xF, true)); // row_shr:4
  v += __int_as_float(__builtin_amdgcn_update_dpp(0, __float_as_int(v), 0x118, 0xF, 0xF, true)); // row_shr:8
  v += __int_as_float(__builtin_amdgcn_update_dpp(0, __float_as_int(v), 0x142, 0xF, 0xF, true)); // row_bcast:15
  return v;
}

__global__ __launch_bounds__(512, 4) void perturb_kernel(
    const float* __restrict__ counts, const float* __restrict__ otu,
    const float* __restrict__ comm,   const float* __restrict__ cw,
    const float* __restrict__ cc,     const float* __restrict__ gamma_p,
    float* __restrict__ out) {
  // LDS: 80128 + 800 = 80928 B -> 2 blocks/CU (<= 81920)
  __shared__ float s_lm[LM_ALLOC];     // [k][o] log(mix+eps) for this block's g
  __shared__ float s_bias[Sc * Kc];    // [s][k] log(comm+eps) for this g

  const int tid  = threadIdx.x;
  const int bid  = blockIdx.x;
  const int g    = bid % Gc;
  const int bg   = bid / Gc;
  const int blocksg = (gridDim.x + (Gc - 1) - g) / Gc;

  const float cwg = cw[g];
  const float gam = gamma_p[0];

  // ---- stage log_mix + bias into LDS ----
  for (int idx = tid; idx < LM_ALLOC; idx += blockDim.x) {
    float v = 0.f;
    if (idx < LM_ELEMS) {
      int o = idx % Oc;                 // idx = k*1000 + o, otu is [K][O] so otu[idx]
      float mix = otu[idx] * (1.f - cwg) + cwg * cc[g * Oc + o];
      v = __logf(mix + EPSF);
    }
    s_lm[idx] = v;
  }
  for (int idx = tid; idx < Sc * Kc; idx += blockDim.x) {
    int s = idx / Kc, k = idx - s * Kc;
    s_bias[idx] = __logf(comm[(k * Gc + g) * Sc + s] + EPSF);
  }
  __syncthreads();

  const int wave = tid >> 6;
  const int lane = tid & 63;
  const int rl   = lane >> 5;          // which 4-row half
  const int osub = lane & 31;          // o-column group within 128-o chunk

  const int waveg  = bg * 8 + wave;    // wave index among this g's waves
  const int nwaveg = blocksg * 8;

  float lsum = 0.f;                    // per-lane LSE accumulator (valid in lanes 31/63)

  for (int gr = waveg; gr < GRANS_PER_G; gr += nwaveg) {
    const int row0 = gr * GRAN_ROWS + rl * 4;               // g-local first row of my 4
    const float* base = counts + (size_t)(g * ROWS_PER_G + row0) * Oc;

    float acc[4][Kc];
#pragma unroll
    for (int r = 0; r < 4; ++r)
#pragma unroll
      for (int k = 0; k < Kc; ++k) acc[r][k] = 0.f;

    // 7 full 128-o chunks
    for (int j = 0; j < 7; ++j) {
      const int ob = j * 128 + (osub << 2);
      float4 c0 = *(const float4*)(base + 0 * Oc + ob);
      float4 c1 = *(const float4*)(base + 1 * Oc + ob);
      float4 c2 = *(const float4*)(base + 2 * Oc + ob);
      float4 c3 = *(const float4*)(base + 3 * Oc + ob);
#pragma unroll
      for (int k = 0; k < Kc; ++k) {
        float4 L = *(const float4*)&s_lm[k * Oc + ob];
        acc[0][k] += c0.x * L.x + c0.y * L.y + c0.z * L.z + c0.w * L.w;
        acc[1][k] += c1.x * L.x + c1.y * L.y + c1.z * L.z + c1.w * L.w;
        acc[2][k] += c2.x * L.x + c2.y * L.y + c2.z * L.z + c2.w * L.w;
        acc[3][k] += c3.x * L.x + c3.y * L.y + c3.z * L.z + c3.w * L.w;
      }
    }
    // tail: o in [896,1000) -> 26 active float4 lanes
    {
      const int ob = 896 + (osub << 2);
      float4 c0 = {0,0,0,0}, c1 = {0,0,0,0}, c2 = {0,0,0,0}, c3 = {0,0,0,0};
      if (osub < 26) {
        c0 = *(const float4*)(base + 0 * Oc + ob);
        c1 = *(const float4*)(base + 1 * Oc + ob);
        c2 = *(const float4*)(base + 2 * Oc + ob);
        c3 = *(const float4*)(base + 3 * Oc + ob);
      }
#pragma unroll
      for (int k = 0; k < Kc; ++k) {
        float4 L = *(const float4*)&s_lm[k * Oc + ob];   // guard pad covers o>=1000
        acc[0][k] += c0.x * L.x + c0.y * L.y + c0.z * L.z + c0.w * L.w;
        acc[1][k] += c1.x * L.x + c1.y * L.y + c1.z * L.z + c1.w * L.w;
        acc[2][k] += c2.x * L.x + c2.y * L.y + c2.z * L.z + c2.w * L.w;
        acc[3][k] += c3.x * L.x + c3.y * L.y + c3.z * L.z + c3.w * L.w;
      }
    }

    // reduce each acc over the 32 o-lanes (DPP, VALU pipe). lanes 31/63 hold sums.
#pragma unroll
    for (int r = 0; r < 4; ++r)
#pragma unroll
      for (int k = 0; k < Kc; ++k) acc[r][k] = red32(acc[r][k]);

    if ((lane & 31) == 31) {
#pragma unroll
      for (int r = 0; r < 4; ++r) {
        const int s = (row0 + r) / Nc;
        const float* bp = &s_bias[s * Kc];
        float m = -3.4e38f;
#pragma unroll
        for (int k = 0; k < Kc; ++k) {
          float x = acc[r][k] + bp[k];
          acc[r][k] = x;
          m = fmaxf(m, x);
        }
        float sum = 0.f;
#pragma unroll
        for (int k = 0; k < Kc; ++k) sum += __expf(gam * (acc[r][k] - m));
        lsum += m + __logf(sum);
      }
    }
  }

  if ((lane & 31) == 31) atomicAdd(out, lsum);
}

extern "C" void kernel_launch(void* const* d_in, const int* in_sizes, int n_in,
                              void* d_out, int out_size, void* d_ws, size_t ws_size,
                              hipStream_t stream) {
  const float* counts = (const float*)d_in[0];
  const float* otu    = (const float*)d_in[1];
  const float* comm   = (const float*)d_in[2];
  const float* cw     = (const float*)d_in[3];
  const float* cc     = (const float*)d_in[4];
  const float* gam    = (const float*)d_in[5];
  float* out = (float*)d_out;

  hipMemsetAsync(out, 0, sizeof(float), stream);
  hipLaunchKernelGGL(perturb_kernel, dim3(512), dim3(512), 0, stream,
                     counts, otu, comm, cw, cc, gam, out);
}

// Round 2
// 884.878 us; speedup vs baseline: 1.8451x; 1.8451x over previous
//
#include <hip/hip_runtime.h>

// PerturbationModel: scores = counts @ log_mix^T (+ log comm bias), LSE over K, grand sum.
// G=3 S=10 N=5000 K=20 O=1000. counts 600 MB fp32 -> memory-bound, floor ~95 us.
//
// R1 fix: __launch_bounds__(512,4) capped VGPR at 128 and the allocator spilled
// acc[4][20] to scratch (2.17 GB WRITE_SIZE, 1049 us). Bound relaxed to (512,2);
// LDS (80928 B) still enforces 2 blocks/CU = 4 waves/SIMD when VGPR <= 128.

#define EPSF 1e-6f
constexpr int Gc = 3, Sc = 10, Nc = 5000, Kc = 20, Oc = 1000;
constexpr int ROWS_PER_G = Sc * Nc;                 // 50000
constexpr int GRAN_ROWS  = 8;                       // rows per wave-granule (2 lane-rows x 4 reg-rows)
constexpr int GRANS_PER_G = ROWS_PER_G / GRAN_ROWS; // 6250 (exact)
constexpr int LM_ELEMS = Kc * Oc;                   // 20000
constexpr int LM_ALLOC = LM_ELEMS + 32;             // guard pad for tail-lane b128 reads

// 32-lane-group sum via DPP (VALU pipe only). Result valid in lanes 31 and 63.
__device__ __forceinline__ float red32(float v) {
  v += __int_as_float(__builtin_amdgcn_update_dpp(0, __float_as_int(v), 0x111, 0xF, 0xF, true)); // row_shr:1
  v += __int_as_float(__builtin_amdgcn_update_dpp(0, __float_as_int(v), 0x112, 0xF, 0xF, true)); // row_shr:2
  v += __int_as_float(__builtin_amdgcn_update_dpp(0, __float_as_int(v), 0x114, 0xF, 0xF, true)); // row_shr:4
  v += __int_as_float(__builtin_amdgcn_update_dpp(0, __float_as_int(v), 0x118, 0xF, 0xF, true)); // row_shr:8
  v += __int_as_float(__builtin_amdgcn_update_dpp(0, __float_as_int(v), 0x142, 0xF, 0xF, true)); // row_bcast:15
  return v;
}

__global__ __launch_bounds__(512, 2) void perturb_kernel(
    const float* __restrict__ counts, const float* __restrict__ otu,
    const float* __restrict__ comm,   const float* __restrict__ cw,
    const float* __restrict__ cc,     const float* __restrict__ gamma_p,
    float* __restrict__ out) {
  // LDS: 80128 + 800 = 80928 B -> 2 blocks/CU (<= 81920 each)
  __shared__ float s_lm[LM_ALLOC];     // [k][o] log(mix+eps) for this block's g
  __shared__ float s_bias[Sc * Kc];    // [s][k] log(comm+eps) for this g

  const int tid  = threadIdx.x;
  const int bid  = blockIdx.x;
  const int g    = bid % Gc;
  const int bg   = bid / Gc;
  const int blocksg = (gridDim.x + (Gc - 1) - g) / Gc;

  const float cwg = cw[g];
  const float gam = gamma_p[0];

  // ---- stage log_mix + bias into LDS ----
  for (int idx = tid; idx < LM_ALLOC; idx += blockDim.x) {
    float v = 0.f;
    if (idx < LM_ELEMS) {
      int o = idx % Oc;                 // idx = k*1000 + o, otu is [K][O] so otu[idx]
      float mix = otu[idx] * (1.f - cwg) + cwg * cc[g * Oc + o];
      v = __logf(mix + EPSF);
    }
    s_lm[idx] = v;
  }
  for (int idx = tid; idx < Sc * Kc; idx += blockDim.x) {
    int s = idx / Kc, k = idx - s * Kc;
    s_bias[idx] = __logf(comm[(k * Gc + g) * Sc + s] + EPSF);
  }
  __syncthreads();

  const int wave = tid >> 6;
  const int lane = tid & 63;
  const int rl   = lane >> 5;          // which 4-row half
  const int osub = lane & 31;          // o-column group within 128-o chunk

  const int waveg  = bg * 8 + wave;    // wave index among this g's waves
  const int nwaveg = blocksg * 8;

  float lsum = 0.f;                    // per-lane LSE accumulator (valid in lanes 31/63)

  for (int gr = waveg; gr < GRANS_PER_G; gr += nwaveg) {
    const int row0 = gr * GRAN_ROWS + rl * 4;               // g-local first row of my 4
    const float* base = counts + (size_t)(g * ROWS_PER_G + row0) * Oc;

    float acc[4][Kc];
#pragma unroll
    for (int r = 0; r < 4; ++r)
#pragma unroll
      for (int k = 0; k < Kc; ++k) acc[r][k] = 0.f;

    // 7 full 128-o chunks
    for (int j = 0; j < 7; ++j) {
      const int ob = j * 128 + (osub << 2);
      float4 c0 = *(const float4*)(base + 0 * Oc + ob);
      float4 c1 = *(const float4*)(base + 1 * Oc + ob);
      float4 c2 = *(const float4*)(base + 2 * Oc + ob);
      float4 c3 = *(const float4*)(base + 3 * Oc + ob);
#pragma unroll
      for (int k = 0; k < Kc; ++k) {
        float4 L = *(const float4*)&s_lm[k * Oc + ob];
        acc[0][k] += c0.x * L.x + c0.y * L.y + c0.z * L.z + c0.w * L.w;
        acc[1][k] += c1.x * L.x + c1.y * L.y + c1.z * L.z + c1.w * L.w;
        acc[2][k] += c2.x * L.x + c2.y * L.y + c2.z * L.z + c2.w * L.w;
        acc[3][k] += c3.x * L.x + c3.y * L.y + c3.z * L.z + c3.w * L.w;
      }
    }
    // tail: o in [896,1000) -> 26 active float4 lanes
    {
      const int ob = 896 + (osub << 2);
      float4 c0 = {0,0,0,0}, c1 = {0,0,0,0}, c2 = {0,0,0,0}, c3 = {0,0,0,0};
      if (osub < 26) {
        c0 = *(const float4*)(base + 0 * Oc + ob);
        c1 = *(const float4*)(base + 1 * Oc + ob);
        c2 = *(const float4*)(base + 2 * Oc + ob);
        c3 = *(const float4*)(base + 3 * Oc + ob);
      }
#pragma unroll
      for (int k = 0; k < Kc; ++k) {
        float4 L = *(const float4*)&s_lm[k * Oc + ob];   // guard pad covers o>=1000
        acc[0][k] += c0.x * L.x + c0.y * L.y + c0.z * L.z + c0.w * L.w;
        acc[1][k] += c1.x * L.x + c1.y * L.y + c1.z * L.z + c1.w * L.w;
        acc[2][k] += c2.x * L.x + c2.y * L.y + c2.z * L.z + c2.w * L.w;
        acc[3][k] += c3.x * L.x + c3.y * L.y + c3.z * L.z + c3.w * L.w;
      }
    }

    // reduce each acc over the 32 o-lanes (DPP, VALU pipe). lanes 31/63 hold sums.
#pragma unroll
    for (int r = 0; r < 4; ++r)
#pragma unroll
      for (int k = 0; k < Kc; ++k) acc[r][k] = red32(acc[r][k]);

    if ((lane & 31) == 31) {
#pragma unroll
      for (int r = 0; r < 4; ++r) {
        const int s = (row0 + r) / Nc;
        const float* bp = &s_bias[s * Kc];
        float m = -3.4e38f;
#pragma unroll
        for (int k = 0; k < Kc; ++k) {
          float x = acc[r][k] + bp[k];
          acc[r][k] = x;
          m = fmaxf(m, x);
        }
        float sum = 0.f;
#pragma unroll
        for (int k = 0; k < Kc; ++k) sum += __expf(gam * (acc[r][k] - m));
        lsum += m + __logf(sum);
      }
    }
  }

  if ((lane & 31) == 31) atomicAdd(out, lsum);
}

extern "C" void kernel_launch(void* const* d_in, const int* in_sizes, int n_in,
                              void* d_out, int out_size, void* d_ws, size_t ws_size,
                              hipStream_t stream) {
  const float* counts = (const float*)d_in[0];
  const float* otu    = (const float*)d_in[1];
  const float* comm   = (const float*)d_in[2];
  const float* cw     = (const float*)d_in[3];
  const float* cc     = (const float*)d_in[4];
  const float* gam    = (const float*)d_in[5];
  float* out = (float*)d_out;

  hipMemsetAsync(out, 0, sizeof(float), stream);
  hipLaunchKernelGGL(perturb_kernel, dim3(512), dim3(512), 0, stream,
                     counts, otu, comm, cw, cc, gam, out);
}